// Round 1
// baseline (365.774 us; speedup 1.0000x reference)
//
#include <hip/hip_runtime.h>
#include <cstdint>

#define DIMN 1024
#define SEQ  2048
#define BATCH 2
#define MTOT (BATCH*SEQ)      // 4096 rows
#define NELEM_ACT (MTOT*DIMN) // 4,194,304
#define NELEM_W   (DIMN*DIMN) // 1,048,576

typedef __attribute__((ext_vector_type(8))) short   s16x8;
typedef __attribute__((ext_vector_type(4))) float   f32x4v;

__device__ __forceinline__ float b2f(unsigned short u) {
  union { unsigned int i; float f; } x; x.i = ((unsigned int)u) << 16; return x.f;
}
__device__ __forceinline__ unsigned short f2b(float f) {
  unsigned int x = __float_as_uint(f);
  return (unsigned short)((x + 0x7fffu + ((x >> 16) & 1u)) >> 16);
}

__device__ __forceinline__ void gload16(const void* g, void* l) {
  __builtin_amdgcn_global_load_lds((const __attribute__((address_space(1))) void*)g,
                                   (__attribute__((address_space(3))) void*)l,
                                   16, 0, 0);
}

// ---------------------------------------------------------------------------
// fp32 -> bf16 hi/lo split (elementwise, float4-vectorized)
// ---------------------------------------------------------------------------
__global__ __launch_bounds__(256) void split_cvt_kernel(
    const float* __restrict__ in, unsigned short* __restrict__ hi,
    unsigned short* __restrict__ lo, int n) {
  int i = (blockIdx.x * 256 + threadIdx.x) * 4;
  if (i >= n) return;
  float4 v = *(const float4*)(in + i);
  unsigned short h0 = f2b(v.x), h1 = f2b(v.y), h2 = f2b(v.z), h3 = f2b(v.w);
  ushort4 hv; hv.x = h0; hv.y = h1; hv.z = h2; hv.w = h3;
  *(ushort4*)(hi + i) = hv;
  ushort4 lv;
  lv.x = f2b(v.x - b2f(h0)); lv.y = f2b(v.y - b2f(h1));
  lv.z = f2b(v.z - b2f(h2)); lv.w = f2b(v.w - b2f(h3));
  *(ushort4*)(lo + i) = lv;
}

// ---------------------------------------------------------------------------
// fp32 [R][C] -> bf16 transposed [C][R], optional lo part
// ---------------------------------------------------------------------------
__global__ __launch_bounds__(256) void transpose_kernel(
    const float* __restrict__ in, unsigned short* __restrict__ hi,
    unsigned short* __restrict__ lo, int R, int C) {
  __shared__ float t[32][33];
  int tx = threadIdx.x & 31, ty = threadIdx.x >> 5;  // 32 x 8
  int r0 = blockIdx.y * 32, c0 = blockIdx.x * 32;
  #pragma unroll
  for (int i = 0; i < 32; i += 8)
    t[ty + i][tx] = in[(size_t)(r0 + ty + i) * C + c0 + tx];
  __syncthreads();
  #pragma unroll
  for (int i = 0; i < 32; i += 8) {
    float v = t[tx][ty + i];
    size_t off = (size_t)(c0 + ty + i) * R + r0 + tx;
    unsigned short h = f2b(v);
    hi[off] = h;
    if (lo) lo[off] = f2b(v - b2f(h));
  }
}

// ---------------------------------------------------------------------------
// GEMM: C[M,N] = A[M,K] @ Bt[N,K]^T + bias
// SPLIT: 3-term split-bf16 product (A,Bt have lo parts) for ~fp32 accuracy
// EPI 0: relu, write hi/lo bf16.  EPI 1: write bf16.
// Tile 128x64, BK=32, 256 threads (4 waves as 2x2), mfma_f32_16x16x32_bf16.
// LDS fragment-major layout: 1KB per 16x32 fragment block, lane-contiguous,
// so global_load_lds(16B) staging and ds_read_b128 reads are conflict-free.
// ---------------------------------------------------------------------------
template<bool SPLIT, int EPI>
__global__ __launch_bounds__(256) void gemm_kernel(
    const unsigned short* __restrict__ A,  const unsigned short* __restrict__ Alo,
    const unsigned short* __restrict__ Bt, const unsigned short* __restrict__ Btlo,
    const float* __restrict__ bias,
    unsigned short* __restrict__ O, unsigned short* __restrict__ Olo,
    int Mdim, int Ndim, int Kdim) {
  constexpr int NB = SPLIT ? 24 : 12;        // staged 1KB fragment blocks
  __shared__ unsigned short lds[NB * 512];

  const int tid  = threadIdx.x;
  const int lane = tid & 63;
  const int wave = tid >> 6;
  const int wm = wave >> 1;        // 0..1  (64-row half)
  const int wn = wave & 1;         // 0..1  (32-col half)
  const int frow = lane & 15;
  const int krow = lane >> 4;      // k-group of 8
  const int bm0 = blockIdx.y * 128;
  const int bn0 = blockIdx.x * 64;

  f32x4v acc[4][2] = {};

  for (int k0 = 0; k0 < Kdim; k0 += 32) {
    // ---- stage A (8 blocks), B (4 blocks), [+ lo copies] ----
    for (int i = wave; i < NB; i += 4) {
      int ii = (i < 12) ? i : i - 12;
      bool lopart = (i >= 12);
      const unsigned short* src;
      int row;
      if (ii < 8) { src = lopart ? Alo : A;   row = bm0 + ii * 16 + frow; }
      else        { src = lopart ? Btlo : Bt; row = bn0 + (ii - 8) * 16 + frow; }
      gload16(src + (size_t)row * Kdim + k0 + krow * 8, lds + i * 512);
    }
    __syncthreads();   // drains vmcnt for global_load_lds

    const short* sl = (const short*)lds;
    s16x8 a[4], b[2];
    #pragma unroll
    for (int m = 0; m < 4; ++m)
      a[m] = *(const s16x8*)(sl + (wm * 4 + m) * 512 + lane * 8);
    #pragma unroll
    for (int n = 0; n < 2; ++n)
      b[n] = *(const s16x8*)(sl + (8 + wn * 2 + n) * 512 + lane * 8);

    if constexpr (SPLIT) {
      s16x8 al[4], bl[2];
      #pragma unroll
      for (int m = 0; m < 4; ++m)
        al[m] = *(const s16x8*)(sl + (12 + wm * 4 + m) * 512 + lane * 8);
      #pragma unroll
      for (int n = 0; n < 2; ++n)
        bl[n] = *(const s16x8*)(sl + (20 + wn * 2 + n) * 512 + lane * 8);
      #pragma unroll
      for (int m = 0; m < 4; ++m)
        #pragma unroll
        for (int n = 0; n < 2; ++n) {
          acc[m][n] = __builtin_amdgcn_mfma_f32_16x16x32_bf16(a[m],  b[n],  acc[m][n], 0, 0, 0);
          acc[m][n] = __builtin_amdgcn_mfma_f32_16x16x32_bf16(a[m],  bl[n], acc[m][n], 0, 0, 0);
          acc[m][n] = __builtin_amdgcn_mfma_f32_16x16x32_bf16(al[m], b[n],  acc[m][n], 0, 0, 0);
        }
    } else {
      #pragma unroll
      for (int m = 0; m < 4; ++m)
        #pragma unroll
        for (int n = 0; n < 2; ++n)
          acc[m][n] = __builtin_amdgcn_mfma_f32_16x16x32_bf16(a[m], b[n], acc[m][n], 0, 0, 0);
    }
    __syncthreads();
  }

  // ---- epilogue:  C row = (lane>>4)*4 + r, col = lane&15  (m89-verified) ----
  #pragma unroll
  for (int n = 0; n < 2; ++n) {
    int col = bn0 + wn * 32 + n * 16 + frow;
    float bv = bias[col];
    #pragma unroll
    for (int m = 0; m < 4; ++m) {
      int rbase = bm0 + wm * 64 + m * 16 + krow * 4;
      #pragma unroll
      for (int r = 0; r < 4; ++r) {
        float v = acc[m][n][r] + bv;
        size_t off = (size_t)(rbase + r) * Ndim + col;
        if (EPI == 0) {
          v = fmaxf(v, 0.f);
          unsigned short h = f2b(v);
          O[off] = h;
          Olo[off] = f2b(v - b2f(h));
        } else {
          O[off] = f2b(v);
        }
      }
    }
  }
}

// ---------------------------------------------------------------------------
// Sliding-window attention: one block per (b,s). Window 65 (half=32).
// ---------------------------------------------------------------------------
__global__ __launch_bounds__(256) void attn_kernel(
    const unsigned short* __restrict__ q, const unsigned short* __restrict__ k,
    const unsigned short* __restrict__ v, float* __restrict__ out) {
  __shared__ float qs[DIMN];
  __shared__ float sc[72];
  __shared__ float wts[72];
  const float NEG_INF = -__builtin_huge_valf();

  int bs = blockIdx.x;            // b*SEQ + s
  int s = bs & (SEQ - 1);
  int tid = threadIdx.x, lane = tid & 63, wave = tid >> 6;

  const unsigned short* qp = q + (size_t)bs * DIMN;
  for (int d = tid; d < DIMN; d += 256) qs[d] = b2f(qp[d]);
  __syncthreads();

  // scores (wave w handles offsets w, w+4, ...)
  for (int j = wave; j < 65; j += 4) {
    int pos = s - 32 + j;
    if (pos < 0 || pos >= SEQ) { if (lane == 0) sc[j] = NEG_INF; continue; }
    const unsigned short* kp = k + ((size_t)(bs - s + pos)) * DIMN;
    float dot = 0.f;
    #pragma unroll
    for (int it = 0; it < 2; ++it) {
      int d0 = it * 512 + lane * 8;
      ushort4 ka = *(const ushort4*)(kp + d0);
      ushort4 kb = *(const ushort4*)(kp + d0 + 4);
      float4 qa = *(const float4*)(qs + d0);
      float4 qb = *(const float4*)(qs + d0 + 4);
      dot += qa.x * b2f(ka.x) + qa.y * b2f(ka.y) + qa.z * b2f(ka.z) + qa.w * b2f(ka.w);
      dot += qb.x * b2f(kb.x) + qb.y * b2f(kb.y) + qb.z * b2f(kb.z) + qb.w * b2f(kb.w);
    }
    #pragma unroll
    for (int off = 32; off > 0; off >>= 1) dot += __shfl_xor(dot, off);
    if (lane == 0) sc[j] = dot * 0.03125f;   // 1/sqrt(1024)
  }
  __syncthreads();

  // softmax over 65 scores (wave 0)
  if (wave == 0) {
    float v0 = sc[lane];
    float v1 = (lane == 0) ? sc[64] : NEG_INF;
    float mx = fmaxf(v0, v1);
    #pragma unroll
    for (int off = 32; off > 0; off >>= 1) mx = fmaxf(mx, __shfl_xor(mx, off));
    float p0 = __expf(v0 - mx);
    float p1 = (lane == 0) ? __expf(v1 - mx) : 0.f;
    float sm = p0 + p1;
    #pragma unroll
    for (int off = 32; off > 0; off >>= 1) sm += __shfl_xor(sm, off);
    float inv = 1.f / sm;
    wts[lane] = p0 * inv;
    if (lane == 0) wts[64] = p1 * inv;
  }
  __syncthreads();

  // out[d] = sum_j w_j * v[pos_j][d]; 4 dims per thread
  int d0 = tid * 4;
  float4 acc; acc.x = acc.y = acc.z = acc.w = 0.f;
  int jlo = (s < 32) ? (32 - s) : 0;
  int jhi = (s + 32 > SEQ - 1) ? (SEQ - 1 - s + 32) : 64;
  const unsigned short* vbase = v + (size_t)(bs - s) * DIMN;
  for (int j = jlo; j <= jhi; ++j) {
    float w = wts[j];
    const unsigned short* vp = vbase + (size_t)(s - 32 + j) * DIMN + d0;
    ushort4 vv = *(const ushort4*)vp;
    acc.x += w * b2f(vv.x); acc.y += w * b2f(vv.y);
    acc.z += w * b2f(vv.z); acc.w += w * b2f(vv.w);
  }
  *(float4*)(out + (size_t)bs * DIMN + d0) = acc;
}

// ---------------------------------------------------------------------------
extern "C" void kernel_launch(void* const* d_in, const int* in_sizes, int n_in,
                              void* d_out, int out_size, void* d_ws, size_t ws_size,
                              hipStream_t stream) {
  const float* x  = (const float*)d_in[0];
  const float* w1 = (const float*)d_in[1];
  const float* b1 = (const float*)d_in[2];
  const float* w2 = (const float*)d_in[3];
  const float* b2 = (const float*)d_in[4];
  const float* qw = (const float*)d_in[5];
  const float* qb = (const float*)d_in[6];
  const float* kw = (const float*)d_in[7];
  const float* kb = (const float*)d_in[8];
  const float* vw = (const float*)d_in[9];
  const float* vb = (const float*)d_in[10];
  float* out = (float*)d_out;

  char* ws = (char*)d_ws;
  const size_t SA = (size_t)NELEM_ACT * 2;   // 8,388,608 B
  const size_t SW = (size_t)NELEM_W * 2;     // 2,097,152 B
  unsigned short* xhi   = (unsigned short*)(ws);
  unsigned short* xlo   = (unsigned short*)(ws + SA);
  unsigned short* h_hi  = (unsigned short*)(ws + 2*SA);
  unsigned short* h_lo  = (unsigned short*)(ws + 3*SA);
  unsigned short* m_bf  = (unsigned short*)(ws + 4*SA);
  unsigned short* w1thi = (unsigned short*)(ws + 5*SA);
  unsigned short* w1tlo = (unsigned short*)(ws + 5*SA + SW);
  unsigned short* w2thi = (unsigned short*)(ws + 5*SA + 2*SW);
  unsigned short* w2tlo = (unsigned short*)(ws + 5*SA + 3*SW);
  unsigned short* qwt   = (unsigned short*)(ws + 5*SA + 4*SW);
  unsigned short* kwt   = (unsigned short*)(ws + 5*SA + 5*SW);
  unsigned short* vwt   = (unsigned short*)(ws + 5*SA + 6*SW);
  // dead-buffer reuse for q/k/v
  unsigned short* q_bf = xhi;
  unsigned short* k_bf = xlo;
  unsigned short* v_bf = h_hi;

  dim3 tgrid(32, 32);
  split_cvt_kernel<<<NELEM_ACT / (256 * 4), 256, 0, stream>>>(x, xhi, xlo, NELEM_ACT);
  transpose_kernel<<<tgrid, 256, 0, stream>>>(w1, w1thi, w1tlo, DIMN, DIMN);
  transpose_kernel<<<tgrid, 256, 0, stream>>>(w2, w2thi, w2tlo, DIMN, DIMN);
  transpose_kernel<<<tgrid, 256, 0, stream>>>(qw, qwt, nullptr, DIMN, DIMN);
  transpose_kernel<<<tgrid, 256, 0, stream>>>(kw, kwt, nullptr, DIMN, DIMN);
  transpose_kernel<<<tgrid, 256, 0, stream>>>(vw, vwt, nullptr, DIMN, DIMN);

  dim3 ggrid(DIMN / 64, MTOT / 128);   // (16, 32)
  gemm_kernel<true, 0><<<ggrid, 256, 0, stream>>>(xhi, xlo, w1thi, w1tlo, b1,
                                                  h_hi, h_lo, MTOT, DIMN, DIMN);
  gemm_kernel<true, 1><<<ggrid, 256, 0, stream>>>(h_hi, h_lo, w2thi, w2tlo, b2,
                                                  m_bf, nullptr, MTOT, DIMN, DIMN);
  gemm_kernel<false, 1><<<ggrid, 256, 0, stream>>>(m_bf, nullptr, qwt, nullptr, qb,
                                                   q_bf, nullptr, MTOT, DIMN, DIMN);
  gemm_kernel<false, 1><<<ggrid, 256, 0, stream>>>(m_bf, nullptr, kwt, nullptr, kb,
                                                   k_bf, nullptr, MTOT, DIMN, DIMN);
  gemm_kernel<false, 1><<<ggrid, 256, 0, stream>>>(m_bf, nullptr, vwt, nullptr, vb,
                                                   v_bf, nullptr, MTOT, DIMN, DIMN);

  attn_kernel<<<MTOT, 256, 0, stream>>>(q_bf, k_bf, v_bf, out);
}